// Round 6
// baseline (938.626 us; speedup 1.0000x reference)
//
#include <hip/hip_runtime.h>

#define DIM 1536
#define IMG 1024
#define TXT 256
#define SEQ 1280
#define NH 24
#define HD 64

typedef __attribute__((ext_vector_type(8))) short short8;
typedef __attribute__((ext_vector_type(4))) float f32x4;

__device__ __forceinline__ float bf2f(ushort u) {
    union { unsigned int i; float f; } v; v.i = ((unsigned int)u) << 16; return v.f;
}
__device__ __forceinline__ ushort f2bf(float f) {
    union { unsigned int i; float f; } v; v.f = f;
    unsigned int u = v.i;
    u += 0x7fffu + ((u >> 16) & 1u);
    return (ushort)(u >> 16);
}

// ---------------------------------------------------------------------------
// Input-dtype detector (flag=1 -> fp32 underneath, flag=0 -> bf16).
// ---------------------------------------------------------------------------
__global__ __launch_bounds__(256) void detect_dtype(const void* __restrict__ p,
                                                    int* __restrict__ flag)
{
    __shared__ int cnt;
    if (threadIdx.x == 0) cnt = 0;
    __syncthreads();
    const ushort* u = (const ushort*)p;
    int local = 0;
    for (int i = threadIdx.x; i < 2048; i += 256) {
        ushort v = u[2 * i];
        int e = (v >> 7) & 0xFF;
        if (e >= 0xC0) local++;
    }
    atomicAdd(&cnt, local);
    __syncthreads();
    if (threadIdx.x == 0) flag[0] = (cnt > 16) ? 1 : 0;
}

#define LSTR 40

// ===========================================================================
// Fused QKV GEMM v3: dbuf + prefetch, epilogue writes hi/lo bf16 planes.
// Q,K planes: [s][DIM] bf16. V planes: transposed [h*64+d][SEQ].
// grid.x = 36 (wsel=x/12; n0=(x%12)*128), grid.y = 10 m-tiles (1280 rows).
// ===========================================================================
struct QKVP {
    const void* Xi; const void* Xt;
    const void* W[6];   // wq,wk,wv (img), waddq,waddk,waddv (txt)
    const void* B[6];
    ushort* Yh[3]; ushort* Yl[3];
};

__global__ __launch_bounds__(256) void gemm_qkv_v3(QKVP p, const int* __restrict__ dflag)
{
    __shared__ __align__(16) ushort As[2][128 * LSTR];
    __shared__ __align__(16) ushort Bs[2][128 * LSTR];
    const int dt = dflag[0];
    const int bx = blockIdx.x;
    const int wsel = bx / 12;
    const int n0 = (bx - wsel * 12) * 128;
    const int m0g = blockIdx.y * 128;
    const bool istxt = (m0g >= IMG);
    const int m0 = istxt ? (m0g - IMG) : m0g;
    const void* X  = istxt ? p.Xt : p.Xi;
    const void* Wp = p.W[wsel + (istxt ? 3 : 0)];
    const void* Bp = p.B[wsel + (istxt ? 3 : 0)];
    ushort* Yh = p.Yh[wsel];
    ushort* Yl = p.Yl[wsel];

    const int t = threadIdx.x;
    const int wave = t >> 6, lane = t & 63;
    const int quad = lane >> 4, l16 = lane & 15;
    const int wm = (wave >> 1) * 64, wn = (wave & 1) * 64;

    const int arow = t >> 1, apair = t & 1;
    const int bn8 = (t & 15) << 3, bkk = (t >> 4) << 1;
    const int aps = apair ^ ((arow >> 3) & 1);
    const int adst = arow * LSTR + aps * 16;
    const int bq = bkk >> 3, bo = bkk & 7;

    f32x4 acc[4][4];
#pragma unroll
    for (int i = 0; i < 4; ++i)
#pragma unroll
        for (int j = 0; j < 4; ++j) acc[i][j] = (f32x4)(0.0f);

    float4 raf[4]; uint4 rau[2];
    float4 rbf[4]; uint4 rbu[2];

    auto loadA = [&](int k0) {
        const size_t off = (size_t)(m0 + arow) * DIM + k0 + apair * 16;
        if (dt) {
            const float* xp = (const float*)X + off;
            raf[0] = *(const float4*)xp;       raf[1] = *(const float4*)(xp + 4);
            raf[2] = *(const float4*)(xp + 8); raf[3] = *(const float4*)(xp + 12);
        } else {
            const ushort* xp = (const ushort*)X + off;
            rau[0] = *(const uint4*)xp;
            rau[1] = *(const uint4*)(xp + 8);
        }
    };
    auto loadB = [&](int k0) {
        const size_t off = (size_t)(k0 + bkk) * DIM + n0 + bn8;
        if (dt) {
            const float* wp0 = (const float*)Wp + off;
            rbf[0] = *(const float4*)wp0;         rbf[1] = *(const float4*)(wp0 + 4);
            rbf[2] = *(const float4*)(wp0 + DIM); rbf[3] = *(const float4*)(wp0 + DIM + 4);
        } else {
            const ushort* wp0 = (const ushort*)Wp + off;
            rbu[0] = *(const uint4*)wp0;
            rbu[1] = *(const uint4*)(wp0 + DIM);
        }
    };
    auto storeA = [&](int buf) {
        ushort tmp[16];
        if (dt) {
            const float* xs = (const float*)raf;
#pragma unroll
            for (int i = 0; i < 16; ++i) tmp[i] = f2bf(xs[i]);
        } else {
            *(uint4*)&tmp[0] = rau[0];
            *(uint4*)&tmp[8] = rau[1];
        }
        *(uint4*)&As[buf][adst]     = *(uint4*)&tmp[0];
        *(uint4*)&As[buf][adst + 8] = *(uint4*)&tmp[8];
    };
    auto storeB = [&](int buf) {
        ushort t0[8], t1[8];
        if (dt) {
            const float* f = (const float*)rbf;
#pragma unroll
            for (int j = 0; j < 8; ++j) { t0[j] = f2bf(f[j]); t1[j] = f2bf(f[8 + j]); }
        } else {
            *(uint4*)t0 = rbu[0];
            *(uint4*)t1 = rbu[1];
        }
#pragma unroll
        for (int j = 0; j < 8; ++j) {
            const int rr = bn8 + j;
            const int col = (((bq ^ (rr >> 3)) & 3) << 3) + bo;
            *(unsigned int*)&Bs[buf][rr * LSTR + col] =
                (unsigned int)t0[j] | ((unsigned int)t1[j] << 16);
        }
    };

    loadA(0); loadB(0);
    storeA(0); storeB(0);
    __syncthreads();

    for (int k = 0; k < DIM / 32; ++k) {
        const int cur = k & 1;
        const bool hn = (k + 1) < DIM / 32;
        if (hn) { loadA((k + 1) * 32); loadB((k + 1) * 32); }

        short8 b[4];
#pragma unroll
        for (int j = 0; j < 4; ++j) {
            const int rr = wn + j * 16 + l16;
            const int col = (((quad ^ (rr >> 3)) & 3) << 3);
            b[j] = *(const short8*)&Bs[cur][rr * LSTR + col];
        }
#pragma unroll
        for (int i = 0; i < 4; ++i) {
            const int rr = wm + i * 16 + l16;
            const int ps = (quad >> 1) ^ ((rr >> 3) & 1);
            const int col = ps * 16 + (quad & 1) * 8;
            short8 a = *(const short8*)&As[cur][rr * LSTR + col];
#pragma unroll
            for (int j = 0; j < 4; ++j)
                acc[i][j] = __builtin_amdgcn_mfma_f32_16x16x32_bf16(a, b[j], acc[i][j], 0, 0, 0);
        }
        if (hn) { storeA(cur ^ 1); storeB(cur ^ 1); }
        __syncthreads();
    }

#pragma unroll
    for (int j = 0; j < 4; ++j) {
        const int col = n0 + wn + j * 16 + l16;
        const float bv = dt ? ((const float*)Bp)[col] : bf2f(((const ushort*)Bp)[col]);
#pragma unroll
        for (int i = 0; i < 4; ++i)
#pragma unroll
            for (int r = 0; r < 4; ++r) {
                const int row = m0g + wm + i * 16 + quad * 4 + r;   // s
                const float val = acc[i][j][r] + bv;
                const ushort hi = f2bf(val);
                const ushort lo = f2bf(val - bf2f(hi));
                if (wsel < 2) {   // q,k : [s][DIM]
                    Yh[(size_t)row * DIM + col] = hi;
                    Yl[(size_t)row * DIM + col] = lo;
                } else {          // v : transposed [col][SEQ]  (col = h*64+d)
                    Yh[(size_t)col * SEQ + row] = hi;
                    Yl[(size_t)col * SEQ + row] = lo;
                }
            }
    }
}

// ===========================================================================
// Merged output projections (unchanged from R5). X = 2560 f32 rows (oA|oC).
// ===========================================================================
struct OutP {
    const float* X;
    const void* W[4]; const void* B[4];
    void* out;
};

__global__ __launch_bounds__(256) void gemm_out_v2(OutP p, const int* __restrict__ dflag)
{
    __shared__ __align__(16) ushort Ah[2][128 * LSTR];
    __shared__ __align__(16) ushort Al[2][128 * LSTR];
    __shared__ __align__(16) ushort Bs[2][128 * LSTR];
    const int dt = dflag[0];
    const int n0 = blockIdx.x * 128;
    const int mt = blockIdx.y;
    const int seg = (mt < 8) ? 0 : (mt < 10) ? 1 : (mt < 18) ? 2 : 3;
    const void* Wp = p.W[seg];
    const void* Bp = p.B[seg];
    const int m0 = mt * 128;

    const int t = threadIdx.x;
    const int wave = t >> 6, lane = t & 63;
    const int quad = lane >> 4, l16 = lane & 15;
    const int wm = (wave >> 1) * 64, wn = (wave & 1) * 64;

    const int arow = t >> 1, apair = t & 1;
    const int bn8 = (t & 15) << 3, bkk = (t >> 4) << 1;
    const int aps = apair ^ ((arow >> 3) & 1);
    const int adst = arow * LSTR + aps * 16;
    const int bq = bkk >> 3, bo = bkk & 7;

    f32x4 acc[4][4];
#pragma unroll
    for (int i = 0; i < 4; ++i)
#pragma unroll
        for (int j = 0; j < 4; ++j) acc[i][j] = (f32x4)(0.0f);

    float4 raf[4];
    float4 rbf[4]; uint4 rbu[2];

    auto loadA = [&](int k0) {
        const float* xp = p.X + (size_t)(m0 + arow) * DIM + k0 + apair * 16;
        raf[0] = *(const float4*)xp;       raf[1] = *(const float4*)(xp + 4);
        raf[2] = *(const float4*)(xp + 8); raf[3] = *(const float4*)(xp + 12);
    };
    auto loadB = [&](int k0) {
        const size_t off = (size_t)(k0 + bkk) * DIM + n0 + bn8;
        if (dt) {
            const float* wp0 = (const float*)Wp + off;
            rbf[0] = *(const float4*)wp0;         rbf[1] = *(const float4*)(wp0 + 4);
            rbf[2] = *(const float4*)(wp0 + DIM); rbf[3] = *(const float4*)(wp0 + DIM + 4);
        } else {
            const ushort* wp0 = (const ushort*)Wp + off;
            rbu[0] = *(const uint4*)wp0;
            rbu[1] = *(const uint4*)(wp0 + DIM);
        }
    };
    auto storeA = [&](int buf) {
        ushort hi[16], lo[16];
        const float* xs = (const float*)raf;
#pragma unroll
        for (int i = 0; i < 16; ++i) {
            hi[i] = f2bf(xs[i]);
            lo[i] = f2bf(xs[i] - bf2f(hi[i]));
        }
        *(uint4*)&Ah[buf][adst]     = *(uint4*)&hi[0];
        *(uint4*)&Ah[buf][adst + 8] = *(uint4*)&hi[8];
        *(uint4*)&Al[buf][adst]     = *(uint4*)&lo[0];
        *(uint4*)&Al[buf][adst + 8] = *(uint4*)&lo[8];
    };
    auto storeB = [&](int buf) {
        ushort t0[8], t1[8];
        if (dt) {
            const float* f = (const float*)rbf;
#pragma unroll
            for (int j = 0; j < 8; ++j) { t0[j] = f2bf(f[j]); t1[j] = f2bf(f[8 + j]); }
        } else {
            *(uint4*)t0 = rbu[0];
            *(uint4*)t1 = rbu[1];
        }
#pragma unroll
        for (int j = 0; j < 8; ++j) {
            const int rr = bn8 + j;
            const int col = (((bq ^ (rr >> 3)) & 3) << 3) + bo;
            *(unsigned int*)&Bs[buf][rr * LSTR + col] =
                (unsigned int)t0[j] | ((unsigned int)t1[j] << 16);
        }
    };

    loadA(0); loadB(0);
    storeA(0); storeB(0);
    __syncthreads();

    for (int k = 0; k < DIM / 32; ++k) {
        const int cur = k & 1;
        const bool hn = (k + 1) < DIM / 32;
        if (hn) { loadA((k + 1) * 32); loadB((k + 1) * 32); }

        short8 b[4];
#pragma unroll
        for (int j = 0; j < 4; ++j) {
            const int rr = wn + j * 16 + l16;
            const int col = (((quad ^ (rr >> 3)) & 3) << 3);
            b[j] = *(const short8*)&Bs[cur][rr * LSTR + col];
        }
#pragma unroll
        for (int i = 0; i < 4; ++i) {
            const int rr = wm + i * 16 + l16;
            const int ps = (quad >> 1) ^ ((rr >> 3) & 1);
            const int col = ps * 16 + (quad & 1) * 8;
            short8 ah = *(const short8*)&Ah[cur][rr * LSTR + col];
            short8 al = *(const short8*)&Al[cur][rr * LSTR + col];
#pragma unroll
            for (int j = 0; j < 4; ++j) {
                acc[i][j] = __builtin_amdgcn_mfma_f32_16x16x32_bf16(ah, b[j], acc[i][j], 0, 0, 0);
                acc[i][j] = __builtin_amdgcn_mfma_f32_16x16x32_bf16(al, b[j], acc[i][j], 0, 0, 0);
            }
        }
        if (hn) { storeA(cur ^ 1); storeB(cur ^ 1); }
        __syncthreads();
    }

#pragma unroll
    for (int j = 0; j < 4; ++j) {
        const int col = n0 + wn + j * 16 + l16;
        const float bv = dt ? ((const float*)Bp)[col] : bf2f(((const ushort*)Bp)[col]);
#pragma unroll
        for (int i = 0; i < 4; ++i)
#pragma unroll
            for (int r = 0; r < 4; ++r) {
                const int grow = m0 + wm + i * 16 + quad * 4 + r;
                const size_t o = (size_t)grow * DIM + col;
                const float val = acc[i][j][r] + bv;
                if (dt) ((float*)p.out)[o] = val;
                else    ((ushort*)p.out)[o] = f2bf(val);
            }
    }
}

// ---------------------------------------------------------------------------
// RoPE on packed hi/lo planes (in place), and qx builder from input.
// pe flat layout: s*128 + i*4 + {cos,-sin,sin,cos}.
// ---------------------------------------------------------------------------
__device__ __forceinline__ void pe_load(const void* pe, int dt, size_t off,
                                        float& c00, float& c01, float& c10, float& c11)
{
    if (dt) {
        float4 pv = *(const float4*)((const float*)pe + off);
        c00 = pv.x; c01 = pv.y; c10 = pv.z; c11 = pv.w;
    } else {
        const ushort* pp = (const ushort*)pe + off;
        c00 = bf2f(pp[0]); c01 = bf2f(pp[1]); c10 = bf2f(pp[2]); c11 = bf2f(pp[3]);
    }
}

__global__ __launch_bounds__(256) void rope_packed(
    ushort* __restrict__ ph, ushort* __restrict__ pl,
    const void* __restrict__ pe, const int* __restrict__ dflag, int S)
{
    const int dt = dflag[0];
    int idx = blockIdx.x * 256 + threadIdx.x;
    if (idx >= S * 768) return;
    int s = idx / 768, p = idx - s * 768;
    int col = p << 1, i = p & 31;
    const size_t o = (size_t)s * DIM + col;
    float x0 = bf2f(ph[o])     + bf2f(pl[o]);
    float x1 = bf2f(ph[o + 1]) + bf2f(pl[o + 1]);
    float c00, c01, c10, c11;
    pe_load(pe, dt, (size_t)s * 128 + i * 4, c00, c01, c10, c11);
    float y0 = c00 * x0 + c01 * x1;
    float y1 = c10 * x0 + c11 * x1;
    ushort h0 = f2bf(y0), h1 = f2bf(y1);
    ph[o] = h0;     pl[o]     = f2bf(y0 - bf2f(h0));
    ph[o + 1] = h1; pl[o + 1] = f2bf(y1 - bf2f(h1));
}

__global__ __launch_bounds__(256) void qx_make(
    const void* __restrict__ src, const void* __restrict__ pe,
    ushort* __restrict__ ph, ushort* __restrict__ pl,
    const int* __restrict__ dflag, int S)
{
    const int dt = dflag[0];
    int idx = blockIdx.x * 256 + threadIdx.x;
    if (idx >= S * 768) return;
    int s = idx / 768, p = idx - s * 768;
    int col = p << 1, i = p & 31;
    float x0, x1;
    if (dt) {
        float2 xv = *(const float2*)((const float*)src + (size_t)s * DIM + col);
        x0 = xv.x; x1 = xv.y;
    } else {
        const ushort* sp = (const ushort*)src + (size_t)s * DIM + col;
        x0 = bf2f(sp[0]); x1 = bf2f(sp[1]);
    }
    float c00, c01, c10, c11;
    pe_load(pe, dt, (size_t)s * 128 + i * 4, c00, c01, c10, c11);
    float y0 = c00 * x0 + c01 * x1;
    float y1 = c10 * x0 + c11 * x1;
    const size_t o = (size_t)s * DIM + col;
    ushort h0 = f2bf(y0), h1 = f2bf(y1);
    ph[o] = h0;     pl[o]     = f2bf(y0 - bf2f(h0));
    ph[o + 1] = h1; pl[o + 1] = f2bf(y1 - bf2f(h1));
}

// ---------------------------------------------------------------------------
// Attention v3: barrier-free. Operand frags loaded directly from global
// packed planes (Q,K: [s][DIM] hi/lo; V: [h*64+d][SEQ] hi/lo). LDS only for
// the wave-private P round-trip (8 KB). kv-split via blockIdx.z; partials
// (unnormalized O + m,l) combined by attn_combine.
// ---------------------------------------------------------------------------
__device__ __forceinline__ int swz(int row, int col) {
    return row * 64 + ((((col >> 3) ^ row) & 7) << 3) + (col & 7);
}

__global__ __launch_bounds__(256) void attn_v3(
    const ushort* __restrict__ Qh_, const ushort* __restrict__ Ql_,
    const ushort* __restrict__ Kh_, const ushort* __restrict__ Kl_,
    const ushort* __restrict__ Vh_, const ushort* __restrict__ Vl_,
    float* __restrict__ O0, float* __restrict__ O1,
    float* __restrict__ Mp, float* __restrict__ Lp,
    int kvtiles)
{
    __shared__ ushort Ph[4096];
    const int q0 = blockIdx.x * 64;
    const int h = blockIdx.y;
    const int z = blockIdx.z;
    const int kvbase = z * kvtiles * 64;
    float* O = z ? O1 : O0;

    const int t = threadIdx.x;
    const int wave = t >> 6, lane = t & 63;
    const int quad = lane >> 4, l16 = lane & 15;
    const int wq0 = wave * 16;

    // Q frags direct from global (hi+lo)
    short8 qfh[2], qfl[2];
    {
        const size_t qoff = (size_t)(q0 + wq0 + l16) * DIM + h * HD + quad * 8;
#pragma unroll
        for (int c = 0; c < 2; ++c) {
            qfh[c] = *(const short8*)(Qh_ + qoff + c * 32);
            qfl[c] = *(const short8*)(Ql_ + qoff + c * 32);
        }
    }

    float m_[4], l_[4];
#pragma unroll
    for (int r = 0; r < 4; ++r) { m_[r] = -3e38f; l_[r] = 0.0f; }
    f32x4 Oacc[4];
#pragma unroll
    for (int j = 0; j < 4; ++j) Oacc[j] = (f32x4)(0.0f);

    for (int tt = 0; tt < kvtiles; ++tt) {
        const int kv0 = kvbase + tt * 64;

        // ---- S = Q K^T (3-term), B-frags direct from global ----
        f32x4 S[4];
#pragma unroll
        for (int j = 0; j < 4; ++j) S[j] = (f32x4)(0.0f);
#pragma unroll
        for (int c = 0; c < 2; ++c) {
            short8 bh[4], bl[4];
#pragma unroll
            for (int j = 0; j < 4; ++j) {
                const size_t koff = (size_t)(kv0 + j * 16 + l16) * DIM + h * HD + c * 32 + quad * 8;
                bh[j] = *(const short8*)(Kh_ + koff);
                bl[j] = *(const short8*)(Kl_ + koff);
            }
#pragma unroll
            for (int j = 0; j < 4; ++j) {
                S[j] = __builtin_amdgcn_mfma_f32_16x16x32_bf16(qfh[c], bh[j], S[j], 0, 0, 0);
                S[j] = __builtin_amdgcn_mfma_f32_16x16x32_bf16(qfl[c], bh[j], S[j], 0, 0, 0);
                S[j] = __builtin_amdgcn_mfma_f32_16x16x32_bf16(qfh[c], bl[j], S[j], 0, 0, 0);
            }
        }
#pragma unroll
        for (int j = 0; j < 4; ++j)
#pragma unroll
            for (int r = 0; r < 4; ++r) S[j][r] *= 0.125f;

        // ---- online softmax (rows quad*4+r, reduce across l16) ----
        float alpha[4];
#pragma unroll
        for (int r = 0; r < 4; ++r) {
            float mx = fmaxf(fmaxf(S[0][r], S[1][r]), fmaxf(S[2][r], S[3][r]));
            mx = fmaxf(mx, __shfl_xor(mx, 1));
            mx = fmaxf(mx, __shfl_xor(mx, 2));
            mx = fmaxf(mx, __shfl_xor(mx, 4));
            mx = fmaxf(mx, __shfl_xor(mx, 8));
            float mn = fmaxf(m_[r], mx);
            alpha[r] = __expf(m_[r] - mn);
            m_[r] = mn;
            float rs = 0.0f;
#pragma unroll
            for (int j = 0; j < 4; ++j) {
                float p = __expf(S[j][r] - mn);
                S[j][r] = p;
                rs += p;
            }
            rs += __shfl_xor(rs, 1);
            rs += __shfl_xor(rs, 2);
            rs += __shfl_xor(rs, 4);
            rs += __shfl_xor(rs, 8);
            l_[r] = l_[r] * alpha[r] + rs;
        }
#pragma unroll
        for (int j = 0; j < 4; ++j)
#pragma unroll
            for (int r = 0; r < 4; ++r) Oacc[j][r] *= alpha[r];

        // ---- P (hi only) via wave-private LDS round-trip ----
        {
            const int prow = wq0 + quad * 4;
#pragma unroll
            for (int j = 0; j < 4; ++j)
#pragma unroll
                for (int r = 0; r < 4; ++r)
                    Ph[swz(prow + r, j * 16 + l16)] = f2bf(S[j][r]);
        }

        // ---- O += P V  (V exact via hi+lo) ----
#pragma unroll
        for (int c = 0; c < 2; ++c) {
            const int pcol = c * 32 + quad * 8;
            short8 pa = *(const short8*)&Ph[swz(wq0 + l16, pcol)];
#pragma unroll
            for (int jn = 0; jn < 4; ++jn) {
                const size_t voff = (size_t)(h * HD + jn * 16 + l16) * SEQ + kv0 + c * 32 + quad * 8;
                short8 vbh = *(const short8*)(Vh_ + voff);
                short8 vbl = *(const short8*)(Vl_ + voff);
                Oacc[jn] = __builtin_amdgcn_mfma_f32_16x16x32_bf16(pa, vbh, Oacc[jn], 0, 0, 0);
                Oacc[jn] = __builtin_amdgcn_mfma_f32_16x16x32_bf16(pa, vbl, Oacc[jn], 0, 0, 0);
            }
        }
    }

    // ---- epilogue: unnormalized O + m,l partials ----
#pragma unroll
    for (int jn = 0; jn < 4; ++jn)
#pragma unroll
        for (int r = 0; r < 4; ++r) {
            const int row = q0 + wq0 + quad * 4 + r;
            O[(size_t)row * DIM + h * HD + jn * 16 + l16] = Oacc[jn][r];
        }
    if (l16 == 0) {
#pragma unroll
        for (int r = 0; r < 4; ++r) {
            const int q = q0 + wq0 + quad * 4 + r;
            Mp[(size_t)(z * NH + h) * 1280 + q] = m_[r];
            Lp[(size_t)(z * NH + h) * 1280 + q] = l_[r];
        }
    }
}

__global__ __launch_bounds__(256) void attn_combine(
    const float* __restrict__ P0, const float* __restrict__ P1,
    const float* __restrict__ Mp, const float* __restrict__ Lp,
    float* __restrict__ dst, int SQ, int split, int addmode)
{
    int idx = blockIdx.x * 256 + threadIdx.x;
    if (idx >= SQ * DIM) return;
    int q = idx / DIM;
    int col = idx - q * DIM;
    int h = col >> 6;
    float v;
    if (split == 2) {
        float m1 = Mp[(size_t)h * 1280 + q];
        float m2 = Mp[(size_t)(NH + h) * 1280 + q];
        float l1 = Lp[(size_t)h * 1280 + q];
        float l2 = Lp[(size_t)(NH + h) * 1280 + q];
        float M = fmaxf(m1, m2);
        float w1 = __expf(m1 - M), w2 = __expf(m2 - M);
        v = (w1 * P0[idx] + w2 * P1[idx]) / (w1 * l1 + w2 * l2);
    } else {
        v = P0[idx] / Lp[(size_t)h * 1280 + q];
    }
    if (addmode) dst[idx] += v; else dst[idx] = v;
}

// ---------------------------------------------------------------------------
extern "C" void kernel_launch(void* const* d_in, const int* in_sizes, int n_in,
                              void* d_out, int out_size, void* d_ws, size_t ws_size,
                              hipStream_t stream) {
    (void)in_sizes; (void)n_in; (void)out_size;
    const void* hs   = d_in[0];
    const void* ehs  = d_in[1];
    const void* hsc  = d_in[2];
    const void* ehsc = d_in[3];
    const void* i2q  = d_in[4];
    const void* pe   = d_in[5];
#define W_(i) ((const void*)d_in[i])

    const size_t SD = (size_t)SEQ * DIM;
    const size_t ID = (size_t)IMG * DIM;
    int*   flag = (int*)d_ws;
    // packed planes (ushorts)
    ushort* qh = (ushort*)((char*)d_ws + 4096);
    ushort* ql  = qh + SD;
    ushort* kh  = ql + SD;
    ushort* kl  = kh + SD;
    ushort* vh  = kl + SD;
    ushort* vl  = vh + SD;
    ushort* qxh = vl + SD;
    ushort* qxl = qxh + ID;
    float* oA = (float*)(qxl + ID);   // 3SD+ID floats in => 4B aligned
    float* oC = oA + SD;
    float* ml = oC + SD;              // m: [0,65536), l: [65536,131072)
    float* scr = ml + 131072;         // SD floats (only used when split==2)
    float* Mp = ml, * Lp = ml + 65536;

    const size_t need2 = 4096 + (3 * SD + ID + 2 * SD + 131072 + SD) * 4;
    const int split = (ws_size >= need2) ? 2 : 1;
    float* part1 = (split == 2) ? scr : oA;   // unused when split==1
    float* xpart0 = (float*)qh;               // q planes dead at attnX time

    dim3 blk(256);
    detect_dtype<<<1, blk, 0, stream>>>(hs, flag);

    auto QKV = [&](const void* Xi, const void* Xt, int iw0, int itw0) {
        QKVP p;
        p.Xi = Xi; p.Xt = Xt;
        for (int j = 0; j < 3; ++j) {
            p.W[j]     = W_(iw0 + 2 * j);  p.B[j]     = W_(iw0 + 2 * j + 1);
            p.W[3 + j] = W_(itw0 + 2 * j); p.B[3 + j] = W_(itw0 + 2 * j + 1);
        }
        p.Yh[0] = qh; p.Yl[0] = ql;
        p.Yh[1] = kh; p.Yl[1] = kl;
        p.Yh[2] = vh; p.Yl[2] = vl;
        gemm_qkv_v3<<<dim3(36, 10), blk, 0, stream>>>(p, flag);
    };
    const int kvt = (SEQ / 64) / split;   // 10 or 20

    // ---- stream A ----
    QKV(hs, ehs, 6, 12);
    attn_v3<<<dim3(SEQ / 64, NH, split), blk, 0, stream>>>(
        qh, ql, kh, kl, vh, vl, oA, part1, Mp, Lp, kvt);
    attn_combine<<<((int)(SEQ * DIM) + 255) / 256, blk, 0, stream>>>(
        oA, part1, Mp, Lp, oA, SEQ, split, 0);

    // ---- stream C ----
    QKV(hsc, ehsc, 22, 28);
    rope_packed<<<(SEQ * 768 + 255) / 256, blk, 0, stream>>>(qh, ql, pe, flag, SEQ);
    rope_packed<<<(SEQ * 768 + 255) / 256, blk, 0, stream>>>(kh, kl, pe, flag, SEQ);
    qx_make<<<(IMG * 768 + 255) / 256, blk, 0, stream>>>(i2q, pe, qxh, qxl, flag, IMG);

    attn_v3<<<dim3(SEQ / 64, NH, split), blk, 0, stream>>>(
        qh, ql, kh, kl, vh, vl, oC, part1, Mp, Lp, kvt);
    attn_combine<<<((int)(SEQ * DIM) + 255) / 256, blk, 0, stream>>>(
        oC, part1, Mp, Lp, oC, SEQ, split, 0);

    // ---- cross (q planes now dead -> reuse as part0) ----
    attn_v3<<<dim3(IMG / 64, NH, split), blk, 0, stream>>>(
        qxh, qxl, kh, kl, vh, vl, xpart0, part1, Mp, Lp, kvt);
    attn_combine<<<((int)(IMG * DIM) + 255) / 256, blk, 0, stream>>>(
        xpart0, part1, Mp, Lp, oA, IMG, split, 1);   // oA += cross

    // ---- output projections (merged, unchanged) ----
    OutP op;
    op.X = oA;
    op.W[0] = W_(18); op.B[0] = W_(19);
    op.W[1] = W_(20); op.B[1] = W_(21);
    op.W[2] = W_(34); op.B[2] = W_(35);
    op.W[3] = W_(36); op.B[3] = W_(37);
    op.out = d_out;
    gemm_out_v2<<<dim3(12, 20), blk, 0, stream>>>(op, flag);
#undef W_
}